// Round 15
// baseline (1019.630 us; speedup 1.0000x reference)
//
#include <hip/hip_runtime.h>
#include <cmath>

namespace {

constexpr int kB = 4;
constexpr int kN = 256;
constexpr int kD = 768;
constexpr int kNL = 8;
constexpr int kDI = 1536;
constexpr int kNH = 24;
constexpr int kHD = 64;
constexpr int kCONV = 1792;   // DI + 2*DS
constexpr int kDPROJ = 3352;  // 2*DI + 2*DS + NH
constexpr int kD3 = 2304;     // 3*D
constexpr int kNCAT = 19968;  // 8*kD3 + 1536 (batched adaLN + final-layer y-mod)
constexpr int kOFF_FL = 18432;  // 8*kD3

typedef __attribute__((ext_vector_type(8))) short short8;
typedef __attribute__((ext_vector_type(4))) short short4v;
typedef __attribute__((ext_vector_type(4))) float f32x4;

__device__ __forceinline__ float siluf(float x) { return x / (1.f + expf(-x)); }

__device__ __forceinline__ short f2bf(float f) {
  unsigned u = __float_as_uint(f);
  unsigned r = (u + 0x7fffu + ((u >> 16) & 1u)) >> 16;
  return (short)r;
}

// async global->LDS, 16B per lane; LDS dest = wave-uniform base + lane*16
__device__ __forceinline__ void gload_lds16(const void* g, void* l) {
  __builtin_amdgcn_global_load_lds(
      (const __attribute__((address_space(1))) void*)g,
      (__attribute__((address_space(3))) void*)l, 16, 0, 0);
}

// combined per-wave load-wait + block barrier; N = newest vmem ops allowed
// to remain in flight (counted vmcnt, T4 — never drain to 0 mid-loop).
template <int N> __device__ __forceinline__ void wait_barrier();
template <> __device__ __forceinline__ void wait_barrier<0>() {
  asm volatile("s_waitcnt vmcnt(0)\n\ts_barrier" ::: "memory");
}
template <> __device__ __forceinline__ void wait_barrier<2>() {
  asm volatile("s_waitcnt vmcnt(2)\n\ts_barrier" ::: "memory");
}
template <> __device__ __forceinline__ void wait_barrier<3>() {
  asm volatile("s_waitcnt vmcnt(3)\n\ts_barrier" ::: "memory");
}
template <> __device__ __forceinline__ void wait_barrier<4>() {
  asm volatile("s_waitcnt vmcnt(4)\n\ts_barrier" ::: "memory");
}

// ------ fused patch embed x2 (+positional) z=0: x->xc, z=1: y->sy(+silu) --
__global__ void patch_embed2_kernel(const float* __restrict__ img0,
                                    const float* __restrict__ w0,
                                    const float* __restrict__ b0,
                                    float* __restrict__ out0,
                                    const float* __restrict__ img1,
                                    const float* __restrict__ w1,
                                    const float* __restrict__ b1,
                                    float* __restrict__ out1,
                                    short* __restrict__ out1_bf) {
  int gid = blockIdx.x * blockDim.x + threadIdx.x;
  if (gid >= kB * kN * kD) return;
  int z = blockIdx.z;
  const float* img = z ? img1 : img0;
  const float* w = z ? w1 : w0;
  const float* bias = z ? b1 : b0;
  int d = gid % kD;
  int n = (gid / kD) % kN;
  int b = gid / (kD * kN);
  int gi = n >> 4, gj = n & 15;
  float acc = bias[d];
#pragma unroll
  for (int c = 0; c < 3; ++c)
#pragma unroll
    for (int pi = 0; pi < 2; ++pi)
#pragma unroll
      for (int pj = 0; pj < 2; ++pj) {
        float v = img[((b * 3 + c) * 32 + gi * 2 + pi) * 32 + gj * 2 + pj];
        acc += v * w[(c * 4 + pi * 2 + pj) * kD + d];
      }
  float pos;
  if (d < 192)       pos = sinf((float)gj * powf(10000.f, -(float)d / 192.f));
  else if (d < 384)  pos = cosf((float)gj * powf(10000.f, -(float)(d - 192) / 192.f));
  else if (d < 576)  pos = sinf((float)gi * powf(10000.f, -(float)(d - 384) / 192.f));
  else               pos = cosf((float)gi * powf(10000.f, -(float)(d - 576) / 192.f));
  acc += pos;
  if (z) {
    float v = siluf(acc);
    out1[gid] = v;
    out1_bf[gid] = f2bf(v);
  } else {
    out0[gid] = acc;
  }
}

// ------- t-embedding arg table: ctst[b][j] = cos/sin(t[b]*freq[j&127]) ----
__global__ void tembed_args_kernel(const float* __restrict__ t,
                                   float* __restrict__ ctst) {
  int idx = blockIdx.x * 256 + threadIdx.x;
  if (idx >= kB * 256) return;
  int b = idx >> 8, j = idx & 255;
  int k = j & 127;
  float f = expf(-9.210340371976184f * (float)k / 128.f);
  float arg = t[b] * f;
  ctst[idx] = (j < 128) ? cosf(arg) : sinf(arg);
}

// ------- split-K coalesced matvec stage 1:  part[l,kc,b,n] ----------------
__global__ __launch_bounds__(256) void splitk_mm_stage1(
    const float* __restrict__ A, const float* __restrict__ W,
    float* __restrict__ part, int K, int Nn, int KC) {
  int n = blockIdx.x * 256 + threadIdx.x;
  int kc = blockIdx.y;
  int l = blockIdx.z;
  if (n >= Nn) return;
  const float* w = W + (size_t)l * K * Nn + (size_t)kc * 64 * Nn + n;
  int kb = kc * 64;
  float a0 = 0.f, a1 = 0.f, a2 = 0.f, a3 = 0.f;
  for (int k = 0; k < 64; ++k) {
    float wv = w[(size_t)k * Nn];
    a0 += A[0 * K + kb + k] * wv;
    a1 += A[1 * K + kb + k] * wv;
    a2 += A[2 * K + kb + k] * wv;
    a3 += A[3 * K + kb + k] * wv;
  }
  size_t base = (((size_t)l * KC + kc) * 4) * Nn + n;
  part[base] = a0;
  part[base + Nn] = a1;
  part[base + 2 * (size_t)Nn] = a2;
  part[base + 3 * (size_t)Nn] = a3;
}

__global__ void splitk_mm_reduce(const float* __restrict__ part,
                                 const float* __restrict__ bias,
                                 float* __restrict__ C, int Nn, int KC, int L,
                                 int act) {
  int idx = blockIdx.x * 256 + threadIdx.x;
  if (idx >= L * 4 * Nn) return;
  int n = idx % Nn;
  int b = (idx / Nn) & 3;
  int l = idx / (4 * Nn);
  float s = bias[(size_t)l * Nn + n];
  for (int kc = 0; kc < KC; ++kc)
    s += part[(((size_t)l * KC + kc) * 4 + b) * Nn + n];
  C[idx] = act ? siluf(s) : s;
}

// ------ st (fp32 [4][768]) -> bf16 padded [64][768]; rows 4..63 zero ------
__global__ void stbf_kernel(const float* __restrict__ st,
                            short* __restrict__ st_bf) {
  int i = blockIdx.x * 256 + threadIdx.x;
  if (i >= 64 * kD) return;
  int r = i / kD;
  st_bf[i] = (r < kB) ? f2bf(st[i]) : (short)0;
}

// ------- transpose + fp32->bf16: W [K][N] -> Wt [Npad][K] (zero-padded) ---
// blockIdx.z selects a layer via element strides sW (floats) / sWt (shorts).
__global__ __launch_bounds__(256) void transposeW_kernel(
    const float* __restrict__ W, short* __restrict__ Wt, int K, int N,
    size_t sW, size_t sWt) {
  W += (size_t)blockIdx.z * sW;
  Wt += (size_t)blockIdx.z * sWt;
  __shared__ float tile[32][33];
  int n0 = blockIdx.x * 32, k0 = blockIdx.y * 32;
  int tid = threadIdx.x;
  int tx = tid & 31, ty = tid >> 5;  // ty in 0..7
#pragma unroll
  for (int i = 0; i < 4; ++i) {
    int k = k0 + ty + i * 8;
    int n = n0 + tx;
    tile[ty + i * 8][tx] = (n < N) ? W[(size_t)k * N + n] : 0.f;
  }
  __syncthreads();
#pragma unroll
  for (int i = 0; i < 4; ++i) {
    int n = n0 + ty + i * 8;  // row of Wt (covers Npad via grid)
    int k = k0 + tx;
    Wt[(size_t)n * K + k] = f2bf(tile[tx][ty + i * 8]);
  }
}

// -------- concat bias: [adaln_b flat 18432][fl_y_b 1536] -> 19968 ---------
__global__ void concat_bias_kernel(const float* __restrict__ a,
                                   const float* __restrict__ b,
                                   float* __restrict__ dst) {
  int i = blockIdx.x * 256 + threadIdx.x;
  if (i < kOFF_FL) dst[i] = a[i];
  else if (i < kNCAT) dst[i] = b[i - kOFF_FL];
}

// ---------------- bf16 MFMA GEMM: C = A(MxK,bf16) @ Bt(Npad x K,bf16)^T ---
// BM x BN block tile, 4 waves of (BM/2)x(BN/2), 16x16x32 MFMA.
// 3-buffer, depth-2 prefetch, counted-vmcnt K-loop — the round-8/10 winner.
// Chunked XCD swizzle + n-major tile order (bijective per z-slice when
// blocks%8==0): each XCD's B slice becomes L2-resident (FETCH halved).
// Split-K (no atomics): blockIdx.z = K-chunk; each chunk writes its own C
// buffer at C + z*czstride; reduction happens in the consumer kernel.
// Decision rule (round-11 lesson): split-K only when the consumer reads the
// output ~once (out-proj, final-proj). zx's consumers read it ~5x -> unsplit.
template <int BM, int BN>
__global__ __launch_bounds__(256) void mfma_gemm(
    const short* __restrict__ A, const short* __restrict__ Bt,
    const float* __restrict__ bias, float* __restrict__ C,
    int Nn, int Ksplit, int Ktot, int ldc, size_t czstride) {
  constexpr int MI = BM / 32;       // 16-row fragments per wave along M
  constexpr int NJ = BN / 32;       // 16-col fragments per wave along N
  constexpr int LPW = BM / 64 + BN / 64;  // vmem instrs per thread per stage
  __shared__ short Als[3 * BM * 32];
  __shared__ short Bls[3 * BN * 32];
  // ---- block id -> tile mapping (XCD-chunked, n-major) ----
  int gx = gridDim.x, gy = gridDim.y;
  int nblk = gx * gy;
  int hl = blockIdx.y * gx + blockIdx.x;  // HW order within z-slice
  int txi, tyi;
  if ((nblk & 7) == 0) {
    int chunk = nblk >> 3;
    int s_id = (hl & 7) * chunk + (hl >> 3);
    txi = s_id / gy;           // n-panel (n-major ordering)
    tyi = s_id % gy;           // m-panel
  } else {
    txi = blockIdx.x;
    tyi = blockIdx.y;
  }
  int m0 = tyi * BM, n0 = txi * BN;
  int koff = blockIdx.z * Ksplit;
  C += (size_t)blockIdx.z * czstride;
  int tid = threadIdx.x;
  int lane = tid & 63, wid = tid >> 6;
  int wr = wid >> 1, wc = wid & 1;
  f32x4 acc[MI][NJ] = {};
  int sm = tid >> 2;            // staged row within 64-row half (0..63)
  int sk = (tid & 3) * 8;       // staged k offset (shorts)
  const int nsteps = Ksplit >> 5;
  auto stage = [&](int buf, int k0) {
#pragma unroll
    for (int h = 0; h < BM / 64; ++h)
      gload_lds16(&A[(size_t)(m0 + h * 64 + sm) * Ktot + koff + k0 + sk],
                  &Als[buf * (BM * 32) + h * 2048 + wid * 512]);
#pragma unroll
    for (int h = 0; h < BN / 64; ++h)
      gload_lds16(&Bt[(size_t)(n0 + h * 64 + sm) * Ktot + koff + k0 + sk],
                  &Bls[buf * (BN * 32) + h * 2048 + wid * 512]);
  };
  stage(0, 0);
  if (nsteps > 1) stage(1, 32);
  int cur = 0;
  for (int s = 0; s < nsteps; ++s) {
    if (s + 1 < nsteps) wait_barrier<LPW>();
    else wait_barrier<0>();
    if (s + 2 < nsteps) stage(cur == 0 ? 2 : cur - 1, (s + 2) << 5);
    short8 av[MI], bv[NJ];
#pragma unroll
    for (int mi = 0; mi < MI; ++mi)
      av[mi] = *(const short8*)&Als[cur * (BM * 32) +
                                    (wr * (BM / 2) + mi * 16 + (lane & 15)) *
                                        32 +
                                    (lane >> 4) * 8];
#pragma unroll
    for (int nj = 0; nj < NJ; ++nj)
      bv[nj] = *(const short8*)&Bls[cur * (BN * 32) +
                                    (wc * (BN / 2) + nj * 16 + (lane & 15)) *
                                        32 +
                                    (lane >> 4) * 8];
#pragma unroll
    for (int mi = 0; mi < MI; ++mi)
#pragma unroll
      for (int nj = 0; nj < NJ; ++nj)
        acc[mi][nj] = __builtin_amdgcn_mfma_f32_16x16x32_bf16(
            av[mi], bv[nj], acc[mi][nj], 0, 0, 0);
    cur = (cur == 2) ? 0 : cur + 1;
  }
#pragma unroll
  for (int mi = 0; mi < MI; ++mi)
#pragma unroll
    for (int nj = 0; nj < NJ; ++nj)
#pragma unroll
      for (int r = 0; r < 4; ++r) {
        int gm = m0 + wr * (BM / 2) + mi * 16 + (lane >> 4) * 4 + r;
        int gn = n0 + wc * (BN / 2) + nj * 16 + (lane & 15);
        if (gn >= Nn) continue;
        C[(size_t)gm * ldc + gn] = acc[mi][nj][r] + (bias ? bias[gn] : 0.f);
      }
}

// ------ LN + modulation (+fused residual reduction) -----------------------
// If p0: xc[row] += g*sum_{z<4}(pz[row]) (4 split-K partials at stride
// pstride) where g = gate from PREVIOUS layer's (gtA row-stride gstride,
// gyA); result written back to xc and fed into LN. Then
// out_bf = bf16(ln(xc)*(1+scale)+shift) with (tA, yA) modulation.
__global__ __launch_bounds__(256) void ln_mod_kernel(
    const float* __restrict__ x, const float* __restrict__ tA,
    const float* __restrict__ yA, short* __restrict__ out_bf, int tstride,
    int ystride, const float* __restrict__ p0, size_t pstride,
    const float* __restrict__ gtA, const float* __restrict__ gyA,
    int gstride, float* __restrict__ xcw) {
  int row = blockIdx.x;  // b*256+n
  int b = row >> 8;
  int tid = threadIdx.x;
  __shared__ float w1[4], w2[4];
  float xr[3];
  float s = 0.f;
#pragma unroll
  for (int k = 0; k < 3; ++k) {
    int i = tid + k * 256;
    float v = x[(size_t)row * kD + i];
    if (p0) {
      float g = gtA[(size_t)b * gstride + 2 * kD + i] +
                gyA[(size_t)row * kNCAT + 2 * kD + i];
      size_t o = (size_t)row * kD + i;
      float ps = p0[o] + p0[o + pstride] + p0[o + 2 * pstride] +
                 p0[o + 3 * pstride];
      v += g * ps;
      xcw[o] = v;
    }
    xr[k] = v;
    s += v;
  }
#pragma unroll
  for (int o = 32; o > 0; o >>= 1) s += __shfl_down(s, o, 64);
  if ((tid & 63) == 0) w1[tid >> 6] = s;
  __syncthreads();
  float mean = (w1[0] + w1[1] + w1[2] + w1[3]) * (1.f / kD);
  float s2 = 0.f;
#pragma unroll
  for (int k = 0; k < 3; ++k) {
    float d = xr[k] - mean;
    s2 += d * d;
  }
#pragma unroll
  for (int o = 32; o > 0; o >>= 1) s2 += __shfl_down(s2, o, 64);
  if ((tid & 63) == 0) w2[tid >> 6] = s2;
  __syncthreads();
  float rstd = rsqrtf((w2[0] + w2[1] + w2[2] + w2[3]) * (1.f / kD) + 1e-6f);
#pragma unroll
  for (int k = 0; k < 3; ++k) {
    int i = tid + k * 256;
    float sc = tA[(size_t)b * tstride + kD + i] +
               yA[(size_t)row * ystride + kD + i];
    float sh = tA[(size_t)b * tstride + i] + yA[(size_t)row * ystride + i];
    float v = (xr[k] - mean) * rstd * (1.f + sc) + sh;
    out_bf[(size_t)row * kD + i] = f2bf(v);
  }
}

// --- fused: causal depthwise conv (width 4)+silu  AND  dt/cumsum scan -----
// dtcum blocks FIRST (blk<96: serial-scan tail starts immediately), then
// conv blocks. conv part vectorized x4. dtcum scan is wave-shuffle based.
__global__ __launch_bounds__(256) void convdt_kernel(
    const float* __restrict__ zx, const float* __restrict__ cw,
    const float* __restrict__ cb, const float* __restrict__ db,
    const float* __restrict__ al, float* __restrict__ xbc,
    short* __restrict__ bB, short* __restrict__ bC, float* __restrict__ dts,
    float* __restrict__ acum) {
  constexpr int kC4 = kCONV / 4;                     // 448
  constexpr int kDtBlocks = kB * kNH;                // 96
  int blk = blockIdx.x;
  if (blk >= kDtBlocks) {
    int idx = (blk - kDtBlocks) * 256 + threadIdx.x;
    int c4 = idx % kC4;
    int row = idx / kC4;  // b*256+n
    int n = row & 255, b = row >> 8;
    int c0 = c4 * 4;
    float acc[4];
    {
      float4 bv = *(const float4*)&cb[c0];
      acc[0] = bv.x; acc[1] = bv.y; acc[2] = bv.z; acc[3] = bv.w;
    }
    float4 taps[4];
#pragma unroll
    for (int j = 0; j < 4; ++j) taps[j] = *(const float4*)&cw[(c0 + j) * 4];
#pragma unroll
    for (int k = 0; k < 4; ++k) {
      int ns = n + k - 3;
      if (ns < 0) continue;
      float4 v =
          *(const float4*)&zx[(size_t)(b * kN + ns) * kDPROJ + kDI + c0];
      acc[0] += v.x * ((const float*)&taps[0])[k];
      acc[1] += v.y * ((const float*)&taps[1])[k];
      acc[2] += v.z * ((const float*)&taps[2])[k];
      acc[3] += v.w * ((const float*)&taps[3])[k];
    }
    float4 outv;
    float* o = (float*)&outv;
#pragma unroll
    for (int j = 0; j < 4; ++j) o[j] = siluf(acc[j]);
    *(float4*)&xbc[(size_t)row * kCONV + c0] = outv;
    if (c0 >= kDI) {
      short4v sv;
#pragma unroll
      for (int j = 0; j < 4; ++j) sv[j] = f2bf(o[j]);
      if (c0 < kDI + 128)
        *(short4v*)&bB[(size_t)row * 128 + (c0 - kDI)] = sv;
      else
        *(short4v*)&bC[(size_t)row * 128 + (c0 - kDI - 128)] = sv;
    }
  } else {
    int bh = blk;  // 0..95
    int b = bh / kNH, h = bh % kNH;
    int n = threadIdx.x;  // 256
    int lane = n & 63;
    __shared__ float wsum[4];
    size_t row = (size_t)(b * kN + n);
    float xv = zx[row * kDPROJ + (kDI + kCONV) + h] + db[h];
    float dt = xv > 20.f ? xv : log1pf(expf(xv));
    dts[row * kNH + h] = dt;
    float v = -expf(al[h]) * dt;
    // wave-level inclusive scan (6 shuffle rounds), then cross-wave offsets
#pragma unroll
    for (int off = 1; off < 64; off <<= 1) {
      float u = __shfl_up(v, off, 64);
      if (lane >= off) v += u;
    }
    if (lane == 63) wsum[n >> 6] = v;
    __syncthreads();
    float base = 0.f;
#pragma unroll
    for (int w = 0; w < 4; ++w)
      if (w < (n >> 6)) base += wsum[w];
    acum[row * kNH + h] = v + base;
  }
}

// -------- y[b,l,h,:] = sum_s scores * xs + D*xs, then *silu(z) -> bf16 ----
// FUSED CB via MFMA from bC/bB (L2-resident). blockIdx.y reversed so the
// heaviest (16-K-tile) blocks dispatch first.
__global__ __launch_bounds__(256) void ssm_y_kernel(
    const short* __restrict__ bCm, const short* __restrict__ bBm,
    const float* __restrict__ acum, const float* __restrict__ dts,
    const float* __restrict__ xbc, const float* __restrict__ zx,
    const float* __restrict__ Dssm, short* __restrict__ ybuf) {
  int bh = blockIdx.z;
  int b = bh / kNH, h = bh % kNH;
  int m0 = (3 - blockIdx.y) * 64;  // heavy blocks (large m0) first
  int tid = threadIdx.x;
  int lane = tid & 63, wid = tid >> 6;
  int tx = tid & 15, ty = tid >> 4;
  __shared__ float As[16][65];
  __shared__ float Xs[16][64];
  float acc[4][4] = {};
  // this wave's CB-tile output rows: l = m0 + wid*16 + (lane>>4)*4 + r
  float acum_l[4];
#pragma unroll
  for (int r = 0; r < 4; ++r) {
    int l = m0 + wid * 16 + (lane >> 4) * 4 + r;
    acum_l[r] = acum[(size_t)(b * kN + l) * kNH + h];
  }
  const short* cRow =
      &bCm[((size_t)(b * kN + m0 + wid * 16 + (lane & 15))) * 128 +
           (lane >> 4) * 8];
  for (int k0 = 0; k0 < kN; k0 += 16) {
    if (k0 > m0 + 63) break;  // strictly upper-triangular tiles are zero
    // ---- CB tile (64 x 16) via MFMA, K=128; wave wid owns rows wid*16.. --
    f32x4 cb = {};
    const short* bRow =
        &bBm[((size_t)(b * kN + k0 + (lane & 15))) * 128 + (lane >> 4) * 8];
#pragma unroll
    for (int ks = 0; ks < 4; ++ks)
      cb = __builtin_amdgcn_mfma_f32_16x16x32_bf16(
          *(const short8*)(cRow + ks * 32), *(const short8*)(bRow + ks * 32),
          cb, 0, 0, 0);
    int ss = k0 + (lane & 15);
    float acum_ss = acum[(size_t)(b * kN + ss) * kNH + h];
    float dts_ss = dts[(size_t)(b * kN + ss) * kNH + h];
    // ---- Xs staging ----
#pragma unroll
    for (int i = 0; i < 4; ++i) {
      int e = tid + i * 256;
      int k = e >> 6, n = e & 63;
      Xs[k][n] = xbc[(size_t)(b * kN + k0 + k) * kCONV + h * kHD + n];
    }
    // ---- As = CB * decay * dt (masked) ----
#pragma unroll
    for (int r = 0; r < 4; ++r) {
      int mloc = wid * 16 + (lane >> 4) * 4 + r;
      int l = m0 + mloc;
      float v = 0.f;
      if (ss <= l) v = cb[r] * expf(acum_l[r] - acum_ss) * dts_ss;
      As[lane & 15][mloc] = v;
    }
    __syncthreads();
#pragma unroll
    for (int kk = 0; kk < 16; ++kk) {
      float a[4], bb[4];
#pragma unroll
      for (int i = 0; i < 4; ++i) a[i] = As[kk][ty * 4 + i];
#pragma unroll
      for (int j = 0; j < 4; ++j) bb[j] = Xs[kk][tx * 4 + j];
#pragma unroll
      for (int i = 0; i < 4; ++i)
#pragma unroll
        for (int j = 0; j < 4; ++j) acc[i][j] += a[i] * bb[j];
    }
    __syncthreads();
  }
  float dd = Dssm[h];
#pragma unroll
  for (int i = 0; i < 4; ++i) {
    int l = m0 + ty * 4 + i;
    size_t row = (size_t)(b * kN + l);
#pragma unroll
    for (int j = 0; j < 4; ++j) {
      int p = tx * 4 + j;
      int col = h * kHD + p;
      float xs_l = xbc[row * kCONV + col];
      float yv = acc[i][j] + dd * xs_l;
      float zv = zx[row * kDPROJ + col];
      ybuf[row * kDI + col] = f2bf(yv * siluf(zv));
    }
  }
}

// ------ unpatchify scatter: sum 4 split-K partials + bias -> out NCHW -----
__global__ void unpatchify_kernel(const float* __restrict__ fpp,
                                  const float* __restrict__ bias,
                                  float* __restrict__ out) {
  constexpr int kFP = kB * kN * 36;  // 36864
  int gid = blockIdx.x * 256 + threadIdx.x;
  if (gid >= kFP) return;
  int j = gid % 36;
  int row = gid / 36;
  int n = row & 255, b = row >> 8;
  int o = j % 9;
  int pj = (j / 9) & 1;
  int pi = j / 18;
  int gi = n >> 4, gj = n & 15;
  float v = fpp[gid] + fpp[kFP + gid] + fpp[2 * kFP + gid] +
            fpp[3 * kFP + gid] + bias[j];
  out[((b * 9 + o) * 32 + gi * 2 + pi) * 32 + (gj * 2 + pj)] = v;
}

// ======================= hf-net conv stack (implicit GEMM) ================
__global__ __launch_bounds__(256) void conv1_kernel(
    const float* __restrict__ Ha, const float* __restrict__ Hb,
    const float* __restrict__ Hc, const float* __restrict__ wa,
    const float* __restrict__ wb, const float* __restrict__ wc,
    const float* __restrict__ ba, const float* __restrict__ bb,
    const float* __restrict__ bc, short* __restrict__ dst) {
  int gid = blockIdx.x * 256 + threadIdx.x;  // (net*4096+px)*64+oc
  if (gid >= 3 * 4096 * 64) return;
  int oc = gid & 63;
  int px = (gid >> 6) & 4095;
  int net = gid >> 18;
  const float* in = net == 0 ? Ha : (net == 1 ? Hb : Hc);
  const float* w = net == 0 ? wa : (net == 1 ? wb : wc);
  const float* bs = net == 0 ? ba : (net == 1 ? bb : bc);
  int xx = px & 31, yy = (px >> 5) & 31, b = px >> 10;
  float acc = bs[oc];
#pragma unroll
  for (int ic = 0; ic < 3; ++ic) {
    const float* ip = in + ((size_t)(b * 3 + ic) << 10);
    const float* wp = w + (oc * 3 + ic) * 9;
#pragma unroll
    for (int ky = 0; ky < 3; ++ky) {
      int ys = yy + ky - 1;
      if (ys < 0 || ys > 31) continue;
#pragma unroll
      for (int kx = 0; kx < 3; ++kx) {
        int xs = xx + kx - 1;
        if (xs < 0 || xs > 31) continue;
        acc += ip[ys * 32 + xs] * wp[ky * 3 + kx];
      }
    }
  }
  dst[gid] = f2bf(fmaxf(acc, 0.f));
}

// z=0: {w2 set, OC=64} -> Bt2 ; z=1: {w3 set, OC=3} -> Bt3
__global__ __launch_bounds__(256) void convw_prep_kernel(
    const float* __restrict__ w2a, const float* __restrict__ w2b,
    const float* __restrict__ w2c, const float* __restrict__ w3a,
    const float* __restrict__ w3b, const float* __restrict__ w3c,
    short* __restrict__ dst2, short* __restrict__ dst3) {
  int idx = blockIdx.x * 256 + threadIdx.x;  // 3*128*576
  if (idx >= 3 * 128 * 576) return;
  int z = blockIdx.z;
  int OC = z ? 3 : 64;
  short* dst = z ? dst3 : dst2;
  int k = idx % 576;
  int row = (idx / 576) & 127;
  int net = idx / (128 * 576);
  const float* w = z ? (net == 0 ? w3a : (net == 1 ? w3b : w3c))
                     : (net == 0 ? w2a : (net == 1 ? w2b : w2c));
  int pos = k >> 6, ic = k & 63;
  float v = (row < OC) ? w[row * 576 + ic * 9 + pos] : 0.f;
  dst[idx] = f2bf(v);
}

template <int EP>
__global__ __launch_bounds__(256) void conv_gemm(
    const short* __restrict__ src, const short* __restrict__ Btall,
    const float* __restrict__ b_a, const float* __restrict__ b_b,
    const float* __restrict__ b_c, const float* __restrict__ r_a,
    const float* __restrict__ r_b, const float* __restrict__ r_c,
    short* __restrict__ dst, float* __restrict__ outp) {
  constexpr int K = 576;
  __shared__ short Als[128 * 32];
  __shared__ short Bls[128 * 32];
  int net = blockIdx.z;
  int m0 = blockIdx.y * 128;
  const float* bias = net == 0 ? b_a : (net == 1 ? b_b : b_c);
  const float* res = net == 0 ? r_a : (net == 1 ? r_b : r_c);
  const short* Bt = Btall + (size_t)net * 128 * K;
  int tid = threadIdx.x;
  int lane = tid & 63, wid = tid >> 6;
  int wr = wid >> 1, wc = wid & 1;
  f32x4 acc[4][4] = {};
  int sm = tid >> 2;
  int sk = (tid & 3) * 8;
  for (int k0 = 0; k0 < K; k0 += 32) {
    int kk = k0 + sk;
    int pos = kk >> 6, ic0 = kk & 63;
    int ky = pos / 3 - 1, kx = pos % 3 - 1;
    uint4 a_st[2], b_st[2];
#pragma unroll
    for (int i = 0; i < 2; ++i) {
      int px = m0 + i * 64 + sm;
      int b = px >> 10;
      int yy = (px >> 5) & 31, xx = px & 31;
      int ys = yy + ky, xs = xx + kx;
      if (ys >= 0 && ys < 32 && xs >= 0 && xs < 32) {
        a_st[i] = *(const uint4*)&src[((size_t)(net * 4096 + (b << 10) +
                                                (ys << 5) + xs)
                                       << 6) +
                                      ic0];
      } else {
        a_st[i] = make_uint4(0u, 0u, 0u, 0u);
      }
      b_st[i] = *(const uint4*)&Bt[(size_t)(i * 64 + sm) * K + kk];
    }
    __syncthreads();
    *(uint4*)&Als[sm * 32 + sk] = a_st[0];
    *(uint4*)&Als[(64 + sm) * 32 + sk] = a_st[1];
    *(uint4*)&Bls[sm * 32 + sk] = b_st[0];
    *(uint4*)&Bls[(64 + sm) * 32 + sk] = b_st[1];
    __syncthreads();
    short8 av[4], bv[4];
#pragma unroll
    for (int mi = 0; mi < 4; ++mi)
      av[mi] = *(const short8*)&Als[(wr * 64 + mi * 16 + (lane & 15)) * 32 +
                                    (lane >> 4) * 8];
#pragma unroll
    for (int nj = 0; nj < 4; ++nj)
      bv[nj] = *(const short8*)&Bls[(wc * 64 + nj * 16 + (lane & 15)) * 32 +
                                    (lane >> 4) * 8];
#pragma unroll
    for (int mi = 0; mi < 4; ++mi)
#pragma unroll
      for (int nj = 0; nj < 4; ++nj)
        acc[mi][nj] = __builtin_amdgcn_mfma_f32_16x16x32_bf16(
            av[mi], bv[nj], acc[mi][nj], 0, 0, 0);
  }
#pragma unroll
  for (int mi = 0; mi < 4; ++mi)
#pragma unroll
    for (int nj = 0; nj < 4; ++nj)
#pragma unroll
      for (int r = 0; r < 4; ++r) {
        int gm = m0 + wr * 64 + mi * 16 + (lane >> 4) * 4 + r;
        int gn = wc * 64 + nj * 16 + (lane & 15);
        float v = acc[mi][nj][r];
        if (EP == 0) {
          if (gn < 64)
            dst[(size_t)(net * 4096 + gm) * 64 + gn] =
                f2bf(fmaxf(v + bias[gn], 0.f));
        } else {
          if (gn < 3) {
            int b = gm >> 10, pix = gm & 1023;
            size_t o = (size_t)(b * 3 + gn) * 1024 + pix;
            outp[36864 + net * 12288 + o] = v + bias[gn] + res[o];
          }
        }
      }
}

}  // namespace

extern "C" void kernel_launch(void* const* d_in, const int* in_sizes, int n_in,
                              void* d_out, int out_size, void* d_ws,
                              size_t ws_size, hipStream_t stream) {
  const float* x = (const float*)d_in[0];
  const float* t = (const float*)d_in[1];
  const float* y = (const float*)d_in[2];
  const float* H[3] = {(const float*)d_in[3], (const float*)d_in[4],
                       (const float*)d_in[5]};
  const float* xe_w = (const float*)d_in[6];
  const float* xe_b = (const float*)d_in[7];
  const float* ye_w = (const float*)d_in[8];
  const float* ye_b = (const float*)d_in[9];
  const float* tw1 = (const float*)d_in[10];
  const float* tb1 = (const float*)d_in[11];
  const float* tw2 = (const float*)d_in[12];
  const float* tb2 = (const float*)d_in[13];
  const float* adaln_w = (const float*)d_in[14];
  const float* adaln_b = (const float*)d_in[15];
  const float* in_w = (const float*)d_in[16];
  const float* conv_w = (const float*)d_in[17];
  const float* conv_b = (const float*)d_in[18];
  const float* dt_bias = (const float*)d_in[19];
  const float* A_log = (const float*)d_in[20];
  const float* D_ssm = (const float*)d_in[21];
  const float* out_w = (const float*)d_in[22];
  const float* fl_t_w = (const float*)d_in[23];
  const float* fl_t_b = (const float*)d_in[24];
  const float* fl_y_w = (const float*)d_in[25];
  const float* fl_y_b = (const float*)d_in[26];
  const float* fl_lin_w = (const float*)d_in[27];
  const float* fl_lin_b = (const float*)d_in[28];

  float* out = (float*)d_out;
  float* ws = (float*)d_ws;

  // workspace layout (floats) — all sizes multiples of 4 (16B alignment)
  size_t off = 0;
  auto alloc = [&](size_t nelem) { float* p = ws + off; off += nelem; return p; };
  float* xc    = alloc((size_t)kB * kN * kD);
  float* sy    = alloc((size_t)kB * kN * kD);
  short* sy_bf = (short*)alloc((size_t)kB * kN * kD / 2);
  float* st    = alloc((size_t)kB * kD);
  float* ht    = alloc((size_t)kB * kD);
  float* ctst  = alloc((size_t)kB * 256);
  float* tA2   = alloc((size_t)64 * kNCAT);           // tA panel [64][19968]
  short* st_bf = (short*)alloc((size_t)64 * kD / 2);  // st bf16, 64 rows
  float* yA8   = alloc((size_t)kB * kN * kNCAT);      // batched adaLN y-mods
  short* xm_bf = (short*)alloc((size_t)kB * kN * kD / 2);
  float* zx    = alloc((size_t)kB * kN * kDPROJ);     // also part
  float* xbc   = alloc((size_t)kB * kN * kCONV);
  float* dts   = alloc((size_t)kB * kN * kNH);
  float* acum  = alloc((size_t)kB * kN * kNH);
  short* ybuf  = (short*)alloc((size_t)kB * kN * kDI / 2);
  float* tfl   = alloc((size_t)kB * 2 * kD);
  float* opart = alloc((size_t)4 * kB * kN * kD);     // out-proj K-partials
  float* fpp   = alloc((size_t)4 * kB * kN * 36);     // final-proj partials
  short* adalnT = (short*)alloc((size_t)kNCAT * kD / 2);  // all adaLN W^T
  float* biascat = alloc(kNCAT);
  short* in_wT = (short*)alloc((size_t)kNL * 3456 * kD / 2);  // 8x in_w^T
  short* out_wT = (short*)alloc((size_t)kNL * 768 * kDI / 2); // 8x out_w^T
  short* Wt    = (short*)alloc((size_t)128 * kD / 2);  // fl_lin^T buf
  short* bBm   = (short*)alloc((size_t)kB * kN * 128 / 2);
  short* bCm   = (short*)alloc((size_t)kB * kN * 128 / 2);
  short* c1bf  = (short*)alloc((size_t)3 * 4096 * 64 / 2);
  short* c2bf  = (short*)alloc((size_t)3 * 4096 * 64 / 2);
  short* Bt2   = (short*)alloc((size_t)3 * 128 * 576 / 2);
  short* Bt3   = (short*)alloc((size_t)3 * 128 * 576 / 2);
  (void)ws_size;

  float* part = zx;          // split-K matvec partials (pre-layer phase)

  dim3 blk(256);

  // embeddings (x->xc; y->sy+silu+bf16) — one fused launch
  patch_embed2_kernel<<<dim3((kB * kN * kD + 255) / 256, 1, 2), blk, 0,
                        stream>>>(x, xe_w, xe_b, xc, y, ye_w, ye_b, sy, sy_bf);

  // ---- batched adaLN: transpose all 8 adaln_w + fl_y_w, concat biases,
  // ---- one fat GEMM  yA8[1024][19968] = sy @ [adaln_w_0..7 | fl_y_w]
  transposeW_kernel<<<dim3(72, 24, kNL), blk, 0, stream>>>(
      adaln_w, adalnT, kD, kD3, (size_t)kD * kD3, (size_t)kD3 * kD);
  transposeW_kernel<<<dim3(48, 24, 1), blk, 0, stream>>>(
      fl_y_w, adalnT + (size_t)kOFF_FL * kD, kD, 2 * kD, 0, 0);
  concat_bias_kernel<<<dim3((kNCAT + 255) / 256), blk, 0, stream>>>(
      adaln_b, fl_y_b, biascat);
  mfma_gemm<128, 128><<<dim3(kNCAT / 128, 8), blk, 0, stream>>>(
      sy_bf, adalnT, biascat, yA8, kNCAT, kD, kD, kNCAT, 0);

  // ---- upfront batched per-layer weight transposes (out of the loop) ----
  transposeW_kernel<<<dim3(108, 24, kNL), blk, 0, stream>>>(
      in_w, in_wT, kD, kDPROJ, (size_t)kD * kDPROJ, (size_t)3456 * kD);
  transposeW_kernel<<<dim3(24, 48, kNL), blk, 0, stream>>>(
      out_w, out_wT, kDI, kD, (size_t)kDI * kD, (size_t)768 * kDI);

  // t-embedding: table -> split-K matvec (ht) -> split-K matvec (st)
  tembed_args_kernel<<<dim3(4), blk, 0, stream>>>(t, ctst);
  splitk_mm_stage1<<<dim3(3, 4, 1), blk, 0, stream>>>(ctst, tw1, part, 256,
                                                      kD, 4);
  splitk_mm_reduce<<<dim3((kB * kD + 255) / 256), blk, 0, stream>>>(
      part, tb1, ht, kD, 4, 1, 1);
  splitk_mm_stage1<<<dim3(3, 12, 1), blk, 0, stream>>>(ht, tw2, part, kD, kD, 12);
  splitk_mm_reduce<<<dim3((kB * kD + 255) / 256), blk, 0, stream>>>(
      part, tb2, st, kD, 12, 1, 1);
  // final-layer t-modulation
  splitk_mm_stage1<<<dim3(6, 12, 1), blk, 0, stream>>>(st, fl_t_w, part, kD,
                                                       2 * kD, 12);
  splitk_mm_reduce<<<dim3((kB * 2 * kD + 255) / 256), blk, 0, stream>>>(
      part, fl_t_b, tfl, 2 * kD, 12, 1, 0);

  // ---- all 8 layers' tA via one small MFMA GEMM on bf16 adalnT ----------
  // tA2[64][19968] = st_bf(64x768, rows>=4 zero) @ adalnT^T + biascat.
  // Per-layer tA = columns l*2304.., row stride kNCAT, rows 0..3 = batch.
  stbf_kernel<<<dim3((64 * kD + 255) / 256), blk, 0, stream>>>(st, st_bf);
  mfma_gemm<64, 128><<<dim3(kNCAT / 128, 1), blk, 0, stream>>>(
      st_bf, adalnT, biascat, tA2, kNCAT, kD, kD, kNCAT, 0);

  // layers
  for (int l = 0; l < kNL; ++l) {
    const float* cw = conv_w + (size_t)l * kCONV * 4;
    const float* cb = conv_b + (size_t)l * kCONV;
    const float* db = dt_bias + (size_t)l * kNH;
    const float* al = A_log + (size_t)l * kNH;
    const float* dd = D_ssm + (size_t)l * kNH;
    const float* tA = tA2 + (size_t)l * kD3;   // row stride kNCAT
    const float* yAl = yA8 + (size_t)l * kD3;  // row stride kNCAT
    // previous layer's out-proj partials + gates (fused into this ln_mod)
    const float* ptA = l ? tA2 + (size_t)(l - 1) * kD3 : nullptr;
    const float* pyA = l ? yA8 + (size_t)(l - 1) * kD3 : nullptr;

    ln_mod_kernel<<<dim3(kB * kN), blk, 0, stream>>>(
        xc, tA, yAl, xm_bf, kNCAT, kNCAT, l ? opart : nullptr,
        (size_t)kB * kN * kD, ptA, pyA, kNCAT, xc);
    // zx = xm @ iw  (M=1024, N=3352 pad 3456, K=768) — BM=128 wide-M tile:
    // 432 blocks (fully resident), 8 MFMAs/wave/step (2x per-step compute
    // amortization vs 64x64; round-14 post-mortem).
    mfma_gemm<128, 64><<<dim3(54, 8), blk, 0, stream>>>(
        xm_bf, in_wT + (size_t)l * 3456 * kD, nullptr, zx, kDPROJ, kD, kD,
        kDPROJ, 0);
    convdt_kernel<<<dim3(kB * kN * (kCONV / 4) / 256 + kB * kNH), blk, 0,
                    stream>>>(zx, cw, cb, db, al, xbc, bBm, bCm, dts, acum);
    ssm_y_kernel<<<dim3(1, kN / 64, kB * kNH), blk, 0, stream>>>(
        bCm, bBm, acum, dts, xbc, zx, dd, ybuf);
    // out-proj partials: opart[z] = ybuf @ ow_chunk  (split-K=4, 12 steps,
    // 768 blocks; reduction + gate fused into the NEXT ln_mod — consumer
    // reads each partial exactly once, per the round-11 decision rule)
    mfma_gemm<64, 64><<<dim3(12, 16, 4), blk, 0, stream>>>(
        ybuf, out_wT + (size_t)l * 768 * kDI, nullptr, opart, kD, 384, kDI,
        kD, (size_t)kB * kN * kD);
  }

  // final layer: fold layer-7 out-proj partials (gates from tA7/yA7), then
  // LN with final-layer modulation (tfl, yfl=yA8[:,kOFF_FL:])
  ln_mod_kernel<<<dim3(kB * kN), blk, 0, stream>>>(
      xc, tfl, yA8 + kOFF_FL, xm_bf, 2 * kD, kNCAT, opart,
      (size_t)kB * kN * kD, tA2 + (size_t)7 * kD3, yA8 + (size_t)7 * kD3,
      kNCAT, xc);
  // final projection via MFMA (N=36 pad 128; split-K=4 partial buffers,
  // summed + biased in unpatchify) + scatter
  transposeW_kernel<<<dim3(4, 24, 1), blk, 0, stream>>>(fl_lin_w, Wt, kD, 36,
                                                        0, 0);
  mfma_gemm<64, 128><<<dim3(1, 16, 4), blk, 0, stream>>>(
      xm_bf, Wt, nullptr, fpp, 36, 192, kD, 36, (size_t)kB * kN * 36);
  unpatchify_kernel<<<dim3((kB * kN * 36 + 255) / 256), blk, 0, stream>>>(
      fpp, fl_lin_b, out);

  // hf-nets via implicit-GEMM MFMA
  const float* w1s[3] = {(const float*)d_in[29], (const float*)d_in[35],
                         (const float*)d_in[41]};
  const float* b1s[3] = {(const float*)d_in[30], (const float*)d_in[36],
                         (const float*)d_in[42]};
  const float* w2s[3] = {(const float*)d_in[31], (const float*)d_in[37],
                         (const float*)d_in[43]};
  const float* b2s[3] = {(const float*)d_in[32], (const float*)d_in[38],
                         (const float*)d_in[44]};
  const float* w3s[3] = {(const float*)d_in[33], (const float*)d_in[39],
                         (const float*)d_in[45]};
  const float* b3s[3] = {(const float*)d_in[34], (const float*)d_in[40],
                         (const float*)d_in[46]};
  convw_prep_kernel<<<dim3((3 * 128 * 576 + 255) / 256, 1, 2), blk, 0,
                      stream>>>(w2s[0], w2s[1], w2s[2], w3s[0], w3s[1],
                                w3s[2], Bt2, Bt3);
  conv1_kernel<<<dim3(3 * 4096 * 64 / 256), blk, 0, stream>>>(
      H[0], H[1], H[2], w1s[0], w1s[1], w1s[2], b1s[0], b1s[1], b1s[2], c1bf);
  conv_gemm<0><<<dim3(1, 32, 3), blk, 0, stream>>>(
      c1bf, Bt2, b2s[0], b2s[1], b2s[2], nullptr, nullptr, nullptr, c2bf,
      nullptr);
  conv_gemm<1><<<dim3(1, 32, 3), blk, 0, stream>>>(
      c2bf, Bt3, b3s[0], b3s[1], b3s[2], H[0], H[1], H[2], nullptr, out);
}

// Round 16
// 995.879 us; speedup vs baseline: 1.0238x; 1.0238x over previous
//
#include <hip/hip_runtime.h>
#include <cmath>

namespace {

constexpr int kB = 4;
constexpr int kN = 256;
constexpr int kD = 768;
constexpr int kNL = 8;
constexpr int kDI = 1536;
constexpr int kNH = 24;
constexpr int kHD = 64;
constexpr int kCONV = 1792;   // DI + 2*DS
constexpr int kDPROJ = 3352;  // 2*DI + 2*DS + NH
constexpr int kD3 = 2304;     // 3*D
constexpr int kNCAT = 19968;  // 8*kD3 + 1536 (batched adaLN + final-layer y-mod)
constexpr int kOFF_FL = 18432;  // 8*kD3

typedef __attribute__((ext_vector_type(8))) short short8;
typedef __attribute__((ext_vector_type(4))) short short4v;
typedef __attribute__((ext_vector_type(4))) float f32x4;

__device__ __forceinline__ float siluf(float x) { return x / (1.f + expf(-x)); }

__device__ __forceinline__ short f2bf(float f) {
  unsigned u = __float_as_uint(f);
  unsigned r = (u + 0x7fffu + ((u >> 16) & 1u)) >> 16;
  return (short)r;
}

// async global->LDS, 16B per lane; LDS dest = wave-uniform base + lane*16
__device__ __forceinline__ void gload_lds16(const void* g, void* l) {
  __builtin_amdgcn_global_load_lds(
      (const __attribute__((address_space(1))) void*)g,
      (__attribute__((address_space(3))) void*)l, 16, 0, 0);
}

// combined per-wave load-wait + block barrier; N = newest vmem ops allowed
// to remain in flight (counted vmcnt, T4 — never drain to 0 mid-loop).
template <int N> __device__ __forceinline__ void wait_barrier();
template <> __device__ __forceinline__ void wait_barrier<0>() {
  asm volatile("s_waitcnt vmcnt(0)\n\ts_barrier" ::: "memory");
}
template <> __device__ __forceinline__ void wait_barrier<2>() {
  asm volatile("s_waitcnt vmcnt(2)\n\ts_barrier" ::: "memory");
}
template <> __device__ __forceinline__ void wait_barrier<3>() {
  asm volatile("s_waitcnt vmcnt(3)\n\ts_barrier" ::: "memory");
}
template <> __device__ __forceinline__ void wait_barrier<4>() {
  asm volatile("s_waitcnt vmcnt(4)\n\ts_barrier" ::: "memory");
}

// ------ fused patch embed x2 (+positional) z=0: x->xc, z=1: y->sy(+silu) --
__global__ void patch_embed2_kernel(const float* __restrict__ img0,
                                    const float* __restrict__ w0,
                                    const float* __restrict__ b0,
                                    float* __restrict__ out0,
                                    const float* __restrict__ img1,
                                    const float* __restrict__ w1,
                                    const float* __restrict__ b1,
                                    float* __restrict__ out1,
                                    short* __restrict__ out1_bf) {
  int gid = blockIdx.x * blockDim.x + threadIdx.x;
  if (gid >= kB * kN * kD) return;
  int z = blockIdx.z;
  const float* img = z ? img1 : img0;
  const float* w = z ? w1 : w0;
  const float* bias = z ? b1 : b0;
  int d = gid % kD;
  int n = (gid / kD) % kN;
  int b = gid / (kD * kN);
  int gi = n >> 4, gj = n & 15;
  float acc = bias[d];
#pragma unroll
  for (int c = 0; c < 3; ++c)
#pragma unroll
    for (int pi = 0; pi < 2; ++pi)
#pragma unroll
      for (int pj = 0; pj < 2; ++pj) {
        float v = img[((b * 3 + c) * 32 + gi * 2 + pi) * 32 + gj * 2 + pj];
        acc += v * w[(c * 4 + pi * 2 + pj) * kD + d];
      }
  float pos;
  if (d < 192)       pos = sinf((float)gj * powf(10000.f, -(float)d / 192.f));
  else if (d < 384)  pos = cosf((float)gj * powf(10000.f, -(float)(d - 192) / 192.f));
  else if (d < 576)  pos = sinf((float)gi * powf(10000.f, -(float)(d - 384) / 192.f));
  else               pos = cosf((float)gi * powf(10000.f, -(float)(d - 576) / 192.f));
  acc += pos;
  if (z) {
    float v = siluf(acc);
    out1[gid] = v;
    out1_bf[gid] = f2bf(v);
  } else {
    out0[gid] = acc;
  }
}

// ------- t-embedding arg table: ctst[b][j] = cos/sin(t[b]*freq[j&127]) ----
__global__ void tembed_args_kernel(const float* __restrict__ t,
                                   float* __restrict__ ctst) {
  int idx = blockIdx.x * 256 + threadIdx.x;
  if (idx >= kB * 256) return;
  int b = idx >> 8, j = idx & 255;
  int k = j & 127;
  float f = expf(-9.210340371976184f * (float)k / 128.f);
  float arg = t[b] * f;
  ctst[idx] = (j < 128) ? cosf(arg) : sinf(arg);
}

// ------- split-K coalesced matvec stage 1:  part[l,kc,b,n] ----------------
__global__ __launch_bounds__(256) void splitk_mm_stage1(
    const float* __restrict__ A, const float* __restrict__ W,
    float* __restrict__ part, int K, int Nn, int KC) {
  int n = blockIdx.x * 256 + threadIdx.x;
  int kc = blockIdx.y;
  int l = blockIdx.z;
  if (n >= Nn) return;
  const float* w = W + (size_t)l * K * Nn + (size_t)kc * 64 * Nn + n;
  int kb = kc * 64;
  float a0 = 0.f, a1 = 0.f, a2 = 0.f, a3 = 0.f;
  for (int k = 0; k < 64; ++k) {
    float wv = w[(size_t)k * Nn];
    a0 += A[0 * K + kb + k] * wv;
    a1 += A[1 * K + kb + k] * wv;
    a2 += A[2 * K + kb + k] * wv;
    a3 += A[3 * K + kb + k] * wv;
  }
  size_t base = (((size_t)l * KC + kc) * 4) * Nn + n;
  part[base] = a0;
  part[base + Nn] = a1;
  part[base + 2 * (size_t)Nn] = a2;
  part[base + 3 * (size_t)Nn] = a3;
}

__global__ void splitk_mm_reduce(const float* __restrict__ part,
                                 const float* __restrict__ bias,
                                 float* __restrict__ C, int Nn, int KC, int L,
                                 int act) {
  int idx = blockIdx.x * 256 + threadIdx.x;
  if (idx >= L * 4 * Nn) return;
  int n = idx % Nn;
  int b = (idx / Nn) & 3;
  int l = idx / (4 * Nn);
  float s = bias[(size_t)l * Nn + n];
  for (int kc = 0; kc < KC; ++kc)
    s += part[(((size_t)l * KC + kc) * 4 + b) * Nn + n];
  C[idx] = act ? siluf(s) : s;
}

// ------ st (fp32 [4][768]) -> bf16 padded [64][768]; rows 4..63 zero ------
__global__ void stbf_kernel(const float* __restrict__ st,
                            short* __restrict__ st_bf) {
  int i = blockIdx.x * 256 + threadIdx.x;
  if (i >= 64 * kD) return;
  int r = i / kD;
  st_bf[i] = (r < kB) ? f2bf(st[i]) : (short)0;
}

// ------- transpose + fp32->bf16: W [K][N] -> Wt [Npad][K] (zero-padded) ---
// blockIdx.z selects a layer via element strides sW (floats) / sWt (shorts).
__global__ __launch_bounds__(256) void transposeW_kernel(
    const float* __restrict__ W, short* __restrict__ Wt, int K, int N,
    size_t sW, size_t sWt) {
  W += (size_t)blockIdx.z * sW;
  Wt += (size_t)blockIdx.z * sWt;
  __shared__ float tile[32][33];
  int n0 = blockIdx.x * 32, k0 = blockIdx.y * 32;
  int tid = threadIdx.x;
  int tx = tid & 31, ty = tid >> 5;  // ty in 0..7
#pragma unroll
  for (int i = 0; i < 4; ++i) {
    int k = k0 + ty + i * 8;
    int n = n0 + tx;
    tile[ty + i * 8][tx] = (n < N) ? W[(size_t)k * N + n] : 0.f;
  }
  __syncthreads();
#pragma unroll
  for (int i = 0; i < 4; ++i) {
    int n = n0 + ty + i * 8;  // row of Wt (covers Npad via grid)
    int k = k0 + tx;
    Wt[(size_t)n * K + k] = f2bf(tile[tx][ty + i * 8]);
  }
}

// -------- concat bias: [adaln_b flat 18432][fl_y_b 1536] -> 19968 ---------
__global__ void concat_bias_kernel(const float* __restrict__ a,
                                   const float* __restrict__ b,
                                   float* __restrict__ dst) {
  int i = blockIdx.x * 256 + threadIdx.x;
  if (i < kOFF_FL) dst[i] = a[i];
  else if (i < kNCAT) dst[i] = b[i - kOFF_FL];
}

// ---------------- bf16 MFMA GEMM: C = A(MxK,bf16) @ Bt(Npad x K,bf16)^T ---
// BM x BN block tile, 4 waves of (BM/2)x(BN/2), 16x16x32 MFMA.
// 3-buffer, depth-2 prefetch, counted-vmcnt K-loop — the round-8/10 winner.
// Chunked XCD swizzle + n-major tile order (bijective per z-slice when
// blocks%8==0): each XCD's B slice becomes L2-resident (FETCH halved).
// Split-K (no atomics): blockIdx.z = K-chunk; each chunk writes its own C
// buffer at C + z*czstride; reduction happens in the consumer kernel.
// Decision rules (measured, rounds 3-15): split-K only when the consumer
// reads the output ~once; 64x64 blocks beat wider tiles for the per-layer
// shapes (more resident blocks > per-block efficiency at low occupancy).
template <int BM, int BN>
__global__ __launch_bounds__(256) void mfma_gemm(
    const short* __restrict__ A, const short* __restrict__ Bt,
    const float* __restrict__ bias, float* __restrict__ C,
    int Nn, int Ksplit, int Ktot, int ldc, size_t czstride) {
  constexpr int MI = BM / 32;       // 16-row fragments per wave along M
  constexpr int NJ = BN / 32;       // 16-col fragments per wave along N
  constexpr int LPW = BM / 64 + BN / 64;  // vmem instrs per thread per stage
  __shared__ short Als[3 * BM * 32];
  __shared__ short Bls[3 * BN * 32];
  // ---- block id -> tile mapping (XCD-chunked, n-major) ----
  int gx = gridDim.x, gy = gridDim.y;
  int nblk = gx * gy;
  int hl = blockIdx.y * gx + blockIdx.x;  // HW order within z-slice
  int txi, tyi;
  if ((nblk & 7) == 0) {
    int chunk = nblk >> 3;
    int s_id = (hl & 7) * chunk + (hl >> 3);
    txi = s_id / gy;           // n-panel (n-major ordering)
    tyi = s_id % gy;           // m-panel
  } else {
    txi = blockIdx.x;
    tyi = blockIdx.y;
  }
  int m0 = tyi * BM, n0 = txi * BN;
  int koff = blockIdx.z * Ksplit;
  C += (size_t)blockIdx.z * czstride;
  int tid = threadIdx.x;
  int lane = tid & 63, wid = tid >> 6;
  int wr = wid >> 1, wc = wid & 1;
  f32x4 acc[MI][NJ] = {};
  int sm = tid >> 2;            // staged row within 64-row half (0..63)
  int sk = (tid & 3) * 8;       // staged k offset (shorts)
  const int nsteps = Ksplit >> 5;
  auto stage = [&](int buf, int k0) {
#pragma unroll
    for (int h = 0; h < BM / 64; ++h)
      gload_lds16(&A[(size_t)(m0 + h * 64 + sm) * Ktot + koff + k0 + sk],
                  &Als[buf * (BM * 32) + h * 2048 + wid * 512]);
#pragma unroll
    for (int h = 0; h < BN / 64; ++h)
      gload_lds16(&Bt[(size_t)(n0 + h * 64 + sm) * Ktot + koff + k0 + sk],
                  &Bls[buf * (BN * 32) + h * 2048 + wid * 512]);
  };
  stage(0, 0);
  if (nsteps > 1) stage(1, 32);
  int cur = 0;
  for (int s = 0; s < nsteps; ++s) {
    if (s + 1 < nsteps) wait_barrier<LPW>();
    else wait_barrier<0>();
    if (s + 2 < nsteps) stage(cur == 0 ? 2 : cur - 1, (s + 2) << 5);
    short8 av[MI], bv[NJ];
#pragma unroll
    for (int mi = 0; mi < MI; ++mi)
      av[mi] = *(const short8*)&Als[cur * (BM * 32) +
                                    (wr * (BM / 2) + mi * 16 + (lane & 15)) *
                                        32 +
                                    (lane >> 4) * 8];
#pragma unroll
    for (int nj = 0; nj < NJ; ++nj)
      bv[nj] = *(const short8*)&Bls[cur * (BN * 32) +
                                    (wc * (BN / 2) + nj * 16 + (lane & 15)) *
                                        32 +
                                    (lane >> 4) * 8];
#pragma unroll
    for (int mi = 0; mi < MI; ++mi)
#pragma unroll
      for (int nj = 0; nj < NJ; ++nj)
        acc[mi][nj] = __builtin_amdgcn_mfma_f32_16x16x32_bf16(
            av[mi], bv[nj], acc[mi][nj], 0, 0, 0);
    cur = (cur == 2) ? 0 : cur + 1;
  }
#pragma unroll
  for (int mi = 0; mi < MI; ++mi)
#pragma unroll
    for (int nj = 0; nj < NJ; ++nj)
#pragma unroll
      for (int r = 0; r < 4; ++r) {
        int gm = m0 + wr * (BM / 2) + mi * 16 + (lane >> 4) * 4 + r;
        int gn = n0 + wc * (BN / 2) + nj * 16 + (lane & 15);
        if (gn >= Nn) continue;
        C[(size_t)gm * ldc + gn] = acc[mi][nj][r] + (bias ? bias[gn] : 0.f);
      }
}

// ------ LN + modulation (+fused residual reduction) -----------------------
// If p0: xc[row] += g*sum_{z<4}(pz[row]) (4 split-K partials at stride
// pstride) where g = gate from PREVIOUS layer's (gtA row-stride gstride,
// gyA); result written back to xc and fed into LN. Then
// out_bf = bf16(ln(xc)*(1+scale)+shift) with (tA, yA) modulation.
__global__ __launch_bounds__(256) void ln_mod_kernel(
    const float* __restrict__ x, const float* __restrict__ tA,
    const float* __restrict__ yA, short* __restrict__ out_bf, int tstride,
    int ystride, const float* __restrict__ p0, size_t pstride,
    const float* __restrict__ gtA, const float* __restrict__ gyA,
    int gstride, float* __restrict__ xcw) {
  int row = blockIdx.x;  // b*256+n
  int b = row >> 8;
  int tid = threadIdx.x;
  __shared__ float w1[4], w2[4];
  float xr[3];
  float s = 0.f;
#pragma unroll
  for (int k = 0; k < 3; ++k) {
    int i = tid + k * 256;
    float v = x[(size_t)row * kD + i];
    if (p0) {
      float g = gtA[(size_t)b * gstride + 2 * kD + i] +
                gyA[(size_t)row * kNCAT + 2 * kD + i];
      size_t o = (size_t)row * kD + i;
      float ps = p0[o] + p0[o + pstride] + p0[o + 2 * pstride] +
                 p0[o + 3 * pstride];
      v += g * ps;
      xcw[o] = v;
    }
    xr[k] = v;
    s += v;
  }
#pragma unroll
  for (int o = 32; o > 0; o >>= 1) s += __shfl_down(s, o, 64);
  if ((tid & 63) == 0) w1[tid >> 6] = s;
  __syncthreads();
  float mean = (w1[0] + w1[1] + w1[2] + w1[3]) * (1.f / kD);
  float s2 = 0.f;
#pragma unroll
  for (int k = 0; k < 3; ++k) {
    float d = xr[k] - mean;
    s2 += d * d;
  }
#pragma unroll
  for (int o = 32; o > 0; o >>= 1) s2 += __shfl_down(s2, o, 64);
  if ((tid & 63) == 0) w2[tid >> 6] = s2;
  __syncthreads();
  float rstd = rsqrtf((w2[0] + w2[1] + w2[2] + w2[3]) * (1.f / kD) + 1e-6f);
#pragma unroll
  for (int k = 0; k < 3; ++k) {
    int i = tid + k * 256;
    float sc = tA[(size_t)b * tstride + kD + i] +
               yA[(size_t)row * ystride + kD + i];
    float sh = tA[(size_t)b * tstride + i] + yA[(size_t)row * ystride + i];
    float v = (xr[k] - mean) * rstd * (1.f + sc) + sh;
    out_bf[(size_t)row * kD + i] = f2bf(v);
  }
}

// --- fused: causal depthwise conv (width 4)+silu  AND  dt/cumsum scan -----
// dtcum blocks FIRST (blk<96: serial-scan tail starts immediately), then
// conv blocks. conv part vectorized x4. dtcum scan is wave-shuffle based.
__global__ __launch_bounds__(256) void convdt_kernel(
    const float* __restrict__ zx, const float* __restrict__ cw,
    const float* __restrict__ cb, const float* __restrict__ db,
    const float* __restrict__ al, float* __restrict__ xbc,
    short* __restrict__ bB, short* __restrict__ bC, float* __restrict__ dts,
    float* __restrict__ acum) {
  constexpr int kC4 = kCONV / 4;                     // 448
  constexpr int kDtBlocks = kB * kNH;                // 96
  int blk = blockIdx.x;
  if (blk >= kDtBlocks) {
    int idx = (blk - kDtBlocks) * 256 + threadIdx.x;
    int c4 = idx % kC4;
    int row = idx / kC4;  // b*256+n
    int n = row & 255, b = row >> 8;
    int c0 = c4 * 4;
    float acc[4];
    {
      float4 bv = *(const float4*)&cb[c0];
      acc[0] = bv.x; acc[1] = bv.y; acc[2] = bv.z; acc[3] = bv.w;
    }
    float4 taps[4];
#pragma unroll
    for (int j = 0; j < 4; ++j) taps[j] = *(const float4*)&cw[(c0 + j) * 4];
#pragma unroll
    for (int k = 0; k < 4; ++k) {
      int ns = n + k - 3;
      if (ns < 0) continue;
      float4 v =
          *(const float4*)&zx[(size_t)(b * kN + ns) * kDPROJ + kDI + c0];
      acc[0] += v.x * ((const float*)&taps[0])[k];
      acc[1] += v.y * ((const float*)&taps[1])[k];
      acc[2] += v.z * ((const float*)&taps[2])[k];
      acc[3] += v.w * ((const float*)&taps[3])[k];
    }
    float4 outv;
    float* o = (float*)&outv;
#pragma unroll
    for (int j = 0; j < 4; ++j) o[j] = siluf(acc[j]);
    *(float4*)&xbc[(size_t)row * kCONV + c0] = outv;
    if (c0 >= kDI) {
      short4v sv;
#pragma unroll
      for (int j = 0; j < 4; ++j) sv[j] = f2bf(o[j]);
      if (c0 < kDI + 128)
        *(short4v*)&bB[(size_t)row * 128 + (c0 - kDI)] = sv;
      else
        *(short4v*)&bC[(size_t)row * 128 + (c0 - kDI - 128)] = sv;
    }
  } else {
    int bh = blk;  // 0..95
    int b = bh / kNH, h = bh % kNH;
    int n = threadIdx.x;  // 256
    int lane = n & 63;
    __shared__ float wsum[4];
    size_t row = (size_t)(b * kN + n);
    float xv = zx[row * kDPROJ + (kDI + kCONV) + h] + db[h];
    float dt = xv > 20.f ? xv : log1pf(expf(xv));
    dts[row * kNH + h] = dt;
    float v = -expf(al[h]) * dt;
    // wave-level inclusive scan (6 shuffle rounds), then cross-wave offsets
#pragma unroll
    for (int off = 1; off < 64; off <<= 1) {
      float u = __shfl_up(v, off, 64);
      if (lane >= off) v += u;
    }
    if (lane == 63) wsum[n >> 6] = v;
    __syncthreads();
    float base = 0.f;
#pragma unroll
    for (int w = 0; w < 4; ++w)
      if (w < (n >> 6)) base += wsum[w];
    acum[row * kNH + h] = v + base;
  }
}

// -------- y[b,l,h,:] = sum_s scores * xs + D*xs, then *silu(z) -> bf16 ----
// FUSED CB via MFMA from bC/bB (L2-resident). blockIdx.y reversed so the
// heaviest (16-K-tile) blocks dispatch first.
__global__ __launch_bounds__(256) void ssm_y_kernel(
    const short* __restrict__ bCm, const short* __restrict__ bBm,
    const float* __restrict__ acum, const float* __restrict__ dts,
    const float* __restrict__ xbc, const float* __restrict__ zx,
    const float* __restrict__ Dssm, short* __restrict__ ybuf) {
  int bh = blockIdx.z;
  int b = bh / kNH, h = bh % kNH;
  int m0 = (3 - blockIdx.y) * 64;  // heavy blocks (large m0) first
  int tid = threadIdx.x;
  int lane = tid & 63, wid = tid >> 6;
  int tx = tid & 15, ty = tid >> 4;
  __shared__ float As[16][65];
  __shared__ float Xs[16][64];
  float acc[4][4] = {};
  // this wave's CB-tile output rows: l = m0 + wid*16 + (lane>>4)*4 + r
  float acum_l[4];
#pragma unroll
  for (int r = 0; r < 4; ++r) {
    int l = m0 + wid * 16 + (lane >> 4) * 4 + r;
    acum_l[r] = acum[(size_t)(b * kN + l) * kNH + h];
  }
  const short* cRow =
      &bCm[((size_t)(b * kN + m0 + wid * 16 + (lane & 15))) * 128 +
           (lane >> 4) * 8];
  for (int k0 = 0; k0 < kN; k0 += 16) {
    if (k0 > m0 + 63) break;  // strictly upper-triangular tiles are zero
    // ---- CB tile (64 x 16) via MFMA, K=128; wave wid owns rows wid*16.. --
    f32x4 cb = {};
    const short* bRow =
        &bBm[((size_t)(b * kN + k0 + (lane & 15))) * 128 + (lane >> 4) * 8];
#pragma unroll
    for (int ks = 0; ks < 4; ++ks)
      cb = __builtin_amdgcn_mfma_f32_16x16x32_bf16(
          *(const short8*)(cRow + ks * 32), *(const short8*)(bRow + ks * 32),
          cb, 0, 0, 0);
    int ss = k0 + (lane & 15);
    float acum_ss = acum[(size_t)(b * kN + ss) * kNH + h];
    float dts_ss = dts[(size_t)(b * kN + ss) * kNH + h];
    // ---- Xs staging ----
#pragma unroll
    for (int i = 0; i < 4; ++i) {
      int e = tid + i * 256;
      int k = e >> 6, n = e & 63;
      Xs[k][n] = xbc[(size_t)(b * kN + k0 + k) * kCONV + h * kHD + n];
    }
    // ---- As = CB * decay * dt (masked) ----
#pragma unroll
    for (int r = 0; r < 4; ++r) {
      int mloc = wid * 16 + (lane >> 4) * 4 + r;
      int l = m0 + mloc;
      float v = 0.f;
      if (ss <= l) v = cb[r] * expf(acum_l[r] - acum_ss) * dts_ss;
      As[lane & 15][mloc] = v;
    }
    __syncthreads();
#pragma unroll
    for (int kk = 0; kk < 16; ++kk) {
      float a[4], bb[4];
#pragma unroll
      for (int i = 0; i < 4; ++i) a[i] = As[kk][ty * 4 + i];
#pragma unroll
      for (int j = 0; j < 4; ++j) bb[j] = Xs[kk][tx * 4 + j];
#pragma unroll
      for (int i = 0; i < 4; ++i)
#pragma unroll
        for (int j = 0; j < 4; ++j) acc[i][j] += a[i] * bb[j];
    }
    __syncthreads();
  }
  float dd = Dssm[h];
#pragma unroll
  for (int i = 0; i < 4; ++i) {
    int l = m0 + ty * 4 + i;
    size_t row = (size_t)(b * kN + l);
#pragma unroll
    for (int j = 0; j < 4; ++j) {
      int p = tx * 4 + j;
      int col = h * kHD + p;
      float xs_l = xbc[row * kCONV + col];
      float yv = acc[i][j] + dd * xs_l;
      float zv = zx[row * kDPROJ + col];
      ybuf[row * kDI + col] = f2bf(yv * siluf(zv));
    }
  }
}

// ------ unpatchify scatter: sum 4 split-K partials + bias -> out NCHW -----
__global__ void unpatchify_kernel(const float* __restrict__ fpp,
                                  const float* __restrict__ bias,
                                  float* __restrict__ out) {
  constexpr int kFP = kB * kN * 36;  // 36864
  int gid = blockIdx.x * 256 + threadIdx.x;
  if (gid >= kFP) return;
  int j = gid % 36;
  int row = gid / 36;
  int n = row & 255, b = row >> 8;
  int o = j % 9;
  int pj = (j / 9) & 1;
  int pi = j / 18;
  int gi = n >> 4, gj = n & 15;
  float v = fpp[gid] + fpp[kFP + gid] + fpp[2 * kFP + gid] +
            fpp[3 * kFP + gid] + bias[j];
  out[((b * 9 + o) * 32 + gi * 2 + pi) * 32 + (gj * 2 + pj)] = v;
}

// ======================= hf-net conv stack (implicit GEMM) ================
__global__ __launch_bounds__(256) void conv1_kernel(
    const float* __restrict__ Ha, const float* __restrict__ Hb,
    const float* __restrict__ Hc, const float* __restrict__ wa,
    const float* __restrict__ wb, const float* __restrict__ wc,
    const float* __restrict__ ba, const float* __restrict__ bb,
    const float* __restrict__ bc, short* __restrict__ dst) {
  int gid = blockIdx.x * 256 + threadIdx.x;  // (net*4096+px)*64+oc
  if (gid >= 3 * 4096 * 64) return;
  int oc = gid & 63;
  int px = (gid >> 6) & 4095;
  int net = gid >> 18;
  const float* in = net == 0 ? Ha : (net == 1 ? Hb : Hc);
  const float* w = net == 0 ? wa : (net == 1 ? wb : wc);
  const float* bs = net == 0 ? ba : (net == 1 ? bb : bc);
  int xx = px & 31, yy = (px >> 5) & 31, b = px >> 10;
  float acc = bs[oc];
#pragma unroll
  for (int ic = 0; ic < 3; ++ic) {
    const float* ip = in + ((size_t)(b * 3 + ic) << 10);
    const float* wp = w + (oc * 3 + ic) * 9;
#pragma unroll
    for (int ky = 0; ky < 3; ++ky) {
      int ys = yy + ky - 1;
      if (ys < 0 || ys > 31) continue;
#pragma unroll
      for (int kx = 0; kx < 3; ++kx) {
        int xs = xx + kx - 1;
        if (xs < 0 || xs > 31) continue;
        acc += ip[ys * 32 + xs] * wp[ky * 3 + kx];
      }
    }
  }
  dst[gid] = f2bf(fmaxf(acc, 0.f));
}

// z=0: {w2 set, OC=64} -> Bt2 ; z=1: {w3 set, OC=3} -> Bt3
__global__ __launch_bounds__(256) void convw_prep_kernel(
    const float* __restrict__ w2a, const float* __restrict__ w2b,
    const float* __restrict__ w2c, const float* __restrict__ w3a,
    const float* __restrict__ w3b, const float* __restrict__ w3c,
    short* __restrict__ dst2, short* __restrict__ dst3) {
  int idx = blockIdx.x * 256 + threadIdx.x;  // 3*128*576
  if (idx >= 3 * 128 * 576) return;
  int z = blockIdx.z;
  int OC = z ? 3 : 64;
  short* dst = z ? dst3 : dst2;
  int k = idx % 576;
  int row = (idx / 576) & 127;
  int net = idx / (128 * 576);
  const float* w = z ? (net == 0 ? w3a : (net == 1 ? w3b : w3c))
                     : (net == 0 ? w2a : (net == 1 ? w2b : w2c));
  int pos = k >> 6, ic = k & 63;
  float v = (row < OC) ? w[row * 576 + ic * 9 + pos] : 0.f;
  dst[idx] = f2bf(v);
}

template <int EP>
__global__ __launch_bounds__(256) void conv_gemm(
    const short* __restrict__ src, const short* __restrict__ Btall,
    const float* __restrict__ b_a, const float* __restrict__ b_b,
    const float* __restrict__ b_c, const float* __restrict__ r_a,
    const float* __restrict__ r_b, const float* __restrict__ r_c,
    short* __restrict__ dst, float* __restrict__ outp) {
  constexpr int K = 576;
  __shared__ short Als[128 * 32];
  __shared__ short Bls[128 * 32];
  int net = blockIdx.z;
  int m0 = blockIdx.y * 128;
  const float* bias = net == 0 ? b_a : (net == 1 ? b_b : b_c);
  const float* res = net == 0 ? r_a : (net == 1 ? r_b : r_c);
  const short* Bt = Btall + (size_t)net * 128 * K;
  int tid = threadIdx.x;
  int lane = tid & 63, wid = tid >> 6;
  int wr = wid >> 1, wc = wid & 1;
  f32x4 acc[4][4] = {};
  int sm = tid >> 2;
  int sk = (tid & 3) * 8;
  for (int k0 = 0; k0 < K; k0 += 32) {
    int kk = k0 + sk;
    int pos = kk >> 6, ic0 = kk & 63;
    int ky = pos / 3 - 1, kx = pos % 3 - 1;
    uint4 a_st[2], b_st[2];
#pragma unroll
    for (int i = 0; i < 2; ++i) {
      int px = m0 + i * 64 + sm;
      int b = px >> 10;
      int yy = (px >> 5) & 31, xx = px & 31;
      int ys = yy + ky, xs = xx + kx;
      if (ys >= 0 && ys < 32 && xs >= 0 && xs < 32) {
        a_st[i] = *(const uint4*)&src[((size_t)(net * 4096 + (b << 10) +
                                                (ys << 5) + xs)
                                       << 6) +
                                      ic0];
      } else {
        a_st[i] = make_uint4(0u, 0u, 0u, 0u);
      }
      b_st[i] = *(const uint4*)&Bt[(size_t)(i * 64 + sm) * K + kk];
    }
    __syncthreads();
    *(uint4*)&Als[sm * 32 + sk] = a_st[0];
    *(uint4*)&Als[(64 + sm) * 32 + sk] = a_st[1];
    *(uint4*)&Bls[sm * 32 + sk] = b_st[0];
    *(uint4*)&Bls[(64 + sm) * 32 + sk] = b_st[1];
    __syncthreads();
    short8 av[4], bv[4];
#pragma unroll
    for (int mi = 0; mi < 4; ++mi)
      av[mi] = *(const short8*)&Als[(wr * 64 + mi * 16 + (lane & 15)) * 32 +
                                    (lane >> 4) * 8];
#pragma unroll
    for (int nj = 0; nj < 4; ++nj)
      bv[nj] = *(const short8*)&Bls[(wc * 64 + nj * 16 + (lane & 15)) * 32 +
                                    (lane >> 4) * 8];
#pragma unroll
    for (int mi = 0; mi < 4; ++mi)
#pragma unroll
      for (int nj = 0; nj < 4; ++nj)
        acc[mi][nj] = __builtin_amdgcn_mfma_f32_16x16x32_bf16(
            av[mi], bv[nj], acc[mi][nj], 0, 0, 0);
  }
#pragma unroll
  for (int mi = 0; mi < 4; ++mi)
#pragma unroll
    for (int nj = 0; nj < 4; ++nj)
#pragma unroll
      for (int r = 0; r < 4; ++r) {
        int gm = m0 + wr * 64 + mi * 16 + (lane >> 4) * 4 + r;
        int gn = wc * 64 + nj * 16 + (lane & 15);
        float v = acc[mi][nj][r];
        if (EP == 0) {
          if (gn < 64)
            dst[(size_t)(net * 4096 + gm) * 64 + gn] =
                f2bf(fmaxf(v + bias[gn], 0.f));
        } else {
          if (gn < 3) {
            int b = gm >> 10, pix = gm & 1023;
            size_t o = (size_t)(b * 3 + gn) * 1024 + pix;
            outp[36864 + net * 12288 + o] = v + bias[gn] + res[o];
          }
        }
      }
}

}  // namespace

extern "C" void kernel_launch(void* const* d_in, const int* in_sizes, int n_in,
                              void* d_out, int out_size, void* d_ws,
                              size_t ws_size, hipStream_t stream) {
  const float* x = (const float*)d_in[0];
  const float* t = (const float*)d_in[1];
  const float* y = (const float*)d_in[2];
  const float* H[3] = {(const float*)d_in[3], (const float*)d_in[4],
                       (const float*)d_in[5]};
  const float* xe_w = (const float*)d_in[6];
  const float* xe_b = (const float*)d_in[7];
  const float* ye_w = (const float*)d_in[8];
  const float* ye_b = (const float*)d_in[9];
  const float* tw1 = (const float*)d_in[10];
  const float* tb1 = (const float*)d_in[11];
  const float* tw2 = (const float*)d_in[12];
  const float* tb2 = (const float*)d_in[13];
  const float* adaln_w = (const float*)d_in[14];
  const float* adaln_b = (const float*)d_in[15];
  const float* in_w = (const float*)d_in[16];
  const float* conv_w = (const float*)d_in[17];
  const float* conv_b = (const float*)d_in[18];
  const float* dt_bias = (const float*)d_in[19];
  const float* A_log = (const float*)d_in[20];
  const float* D_ssm = (const float*)d_in[21];
  const float* out_w = (const float*)d_in[22];
  const float* fl_t_w = (const float*)d_in[23];
  const float* fl_t_b = (const float*)d_in[24];
  const float* fl_y_w = (const float*)d_in[25];
  const float* fl_y_b = (const float*)d_in[26];
  const float* fl_lin_w = (const float*)d_in[27];
  const float* fl_lin_b = (const float*)d_in[28];

  float* out = (float*)d_out;
  float* ws = (float*)d_ws;

  // workspace layout (floats) — all sizes multiples of 4 (16B alignment)
  size_t off = 0;
  auto alloc = [&](size_t nelem) { float* p = ws + off; off += nelem; return p; };
  float* xc    = alloc((size_t)kB * kN * kD);
  float* sy    = alloc((size_t)kB * kN * kD);
  short* sy_bf = (short*)alloc((size_t)kB * kN * kD / 2);
  float* st    = alloc((size_t)kB * kD);
  float* ht    = alloc((size_t)kB * kD);
  float* ctst  = alloc((size_t)kB * 256);
  float* tA2   = alloc((size_t)64 * kNCAT);           // tA panel [64][19968]
  short* st_bf = (short*)alloc((size_t)64 * kD / 2);  // st bf16, 64 rows
  float* yA8   = alloc((size_t)kB * kN * kNCAT);      // batched adaLN y-mods
  short* xm_bf = (short*)alloc((size_t)kB * kN * kD / 2);
  float* zx    = alloc((size_t)kB * kN * kDPROJ);     // also part
  float* xbc   = alloc((size_t)kB * kN * kCONV);
  float* dts   = alloc((size_t)kB * kN * kNH);
  float* acum  = alloc((size_t)kB * kN * kNH);
  short* ybuf  = (short*)alloc((size_t)kB * kN * kDI / 2);
  float* tfl   = alloc((size_t)kB * 2 * kD);
  float* opart = alloc((size_t)4 * kB * kN * kD);     // out-proj K-partials
  float* fpp   = alloc((size_t)4 * kB * kN * 36);     // final-proj partials
  short* adalnT = (short*)alloc((size_t)kNCAT * kD / 2);  // all adaLN W^T
  float* biascat = alloc(kNCAT);
  short* in_wT = (short*)alloc((size_t)kNL * 3456 * kD / 2);  // 8x in_w^T
  short* out_wT = (short*)alloc((size_t)kNL * 768 * kDI / 2); // 8x out_w^T
  short* Wt    = (short*)alloc((size_t)128 * kD / 2);  // fl_lin^T buf
  short* bBm   = (short*)alloc((size_t)kB * kN * 128 / 2);
  short* bCm   = (short*)alloc((size_t)kB * kN * 128 / 2);
  short* c1bf  = (short*)alloc((size_t)3 * 4096 * 64 / 2);
  short* c2bf  = (short*)alloc((size_t)3 * 4096 * 64 / 2);
  short* Bt2   = (short*)alloc((size_t)3 * 128 * 576 / 2);
  short* Bt3   = (short*)alloc((size_t)3 * 128 * 576 / 2);
  (void)ws_size;

  float* part = zx;          // split-K matvec partials (pre-layer phase)

  dim3 blk(256);

  // embeddings (x->xc; y->sy+silu+bf16) — one fused launch
  patch_embed2_kernel<<<dim3((kB * kN * kD + 255) / 256, 1, 2), blk, 0,
                        stream>>>(x, xe_w, xe_b, xc, y, ye_w, ye_b, sy, sy_bf);

  // ---- batched adaLN: transpose all 8 adaln_w + fl_y_w, concat biases,
  // ---- one fat GEMM  yA8[1024][19968] = sy @ [adaln_w_0..7 | fl_y_w]
  transposeW_kernel<<<dim3(72, 24, kNL), blk, 0, stream>>>(
      adaln_w, adalnT, kD, kD3, (size_t)kD * kD3, (size_t)kD3 * kD);
  transposeW_kernel<<<dim3(48, 24, 1), blk, 0, stream>>>(
      fl_y_w, adalnT + (size_t)kOFF_FL * kD, kD, 2 * kD, 0, 0);
  concat_bias_kernel<<<dim3((kNCAT + 255) / 256), blk, 0, stream>>>(
      adaln_b, fl_y_b, biascat);
  mfma_gemm<128, 128><<<dim3(kNCAT / 128, 8), blk, 0, stream>>>(
      sy_bf, adalnT, biascat, yA8, kNCAT, kD, kD, kNCAT, 0);

  // ---- upfront batched per-layer weight transposes (out of the loop) ----
  transposeW_kernel<<<dim3(108, 24, kNL), blk, 0, stream>>>(
      in_w, in_wT, kD, kDPROJ, (size_t)kD * kDPROJ, (size_t)3456 * kD);
  transposeW_kernel<<<dim3(24, 48, kNL), blk, 0, stream>>>(
      out_w, out_wT, kDI, kD, (size_t)kDI * kD, (size_t)768 * kDI);

  // t-embedding: table -> split-K matvec (ht) -> split-K matvec (st)
  tembed_args_kernel<<<dim3(4), blk, 0, stream>>>(t, ctst);
  splitk_mm_stage1<<<dim3(3, 4, 1), blk, 0, stream>>>(ctst, tw1, part, 256,
                                                      kD, 4);
  splitk_mm_reduce<<<dim3((kB * kD + 255) / 256), blk, 0, stream>>>(
      part, tb1, ht, kD, 4, 1, 1);
  splitk_mm_stage1<<<dim3(3, 12, 1), blk, 0, stream>>>(ht, tw2, part, kD, kD, 12);
  splitk_mm_reduce<<<dim3((kB * kD + 255) / 256), blk, 0, stream>>>(
      part, tb2, st, kD, 12, 1, 1);
  // final-layer t-modulation
  splitk_mm_stage1<<<dim3(6, 12, 1), blk, 0, stream>>>(st, fl_t_w, part, kD,
                                                       2 * kD, 12);
  splitk_mm_reduce<<<dim3((kB * 2 * kD + 255) / 256), blk, 0, stream>>>(
      part, fl_t_b, tfl, 2 * kD, 12, 1, 0);

  // ---- all 8 layers' tA via one small MFMA GEMM on bf16 adalnT ----------
  // tA2[64][19968] = st_bf(64x768, rows>=4 zero) @ adalnT^T + biascat.
  // Per-layer tA = columns l*2304.., row stride kNCAT, rows 0..3 = batch.
  stbf_kernel<<<dim3((64 * kD + 255) / 256), blk, 0, stream>>>(st, st_bf);
  mfma_gemm<64, 128><<<dim3(kNCAT / 128, 1), blk, 0, stream>>>(
      st_bf, adalnT, biascat, tA2, kNCAT, kD, kD, kNCAT, 0);

  // layers
  for (int l = 0; l < kNL; ++l) {
    const float* cw = conv_w + (size_t)l * kCONV * 4;
    const float* cb = conv_b + (size_t)l * kCONV;
    const float* db = dt_bias + (size_t)l * kNH;
    const float* al = A_log + (size_t)l * kNH;
    const float* dd = D_ssm + (size_t)l * kNH;
    const float* tA = tA2 + (size_t)l * kD3;   // row stride kNCAT
    const float* yAl = yA8 + (size_t)l * kD3;  // row stride kNCAT
    // previous layer's out-proj partials + gates (fused into this ln_mod)
    const float* ptA = l ? tA2 + (size_t)(l - 1) * kD3 : nullptr;
    const float* pyA = l ? yA8 + (size_t)(l - 1) * kD3 : nullptr;

    ln_mod_kernel<<<dim3(kB * kN), blk, 0, stream>>>(
        xc, tA, yAl, xm_bf, kNCAT, kNCAT, l ? opart : nullptr,
        (size_t)kB * kN * kD, ptA, pyA, kNCAT, xc);
    // zx = xm @ iw  (M=1024, N=3352 pad 3456, K=768) — 864 blocks @ 64x64,
    // the measured optimum (128x64 regressed, round-15 post-mortem)
    mfma_gemm<64, 64><<<dim3(54, 16), blk, 0, stream>>>(
        xm_bf, in_wT + (size_t)l * 3456 * kD, nullptr, zx, kDPROJ, kD, kD,
        kDPROJ, 0);
    convdt_kernel<<<dim3(kB * kN * (kCONV / 4) / 256 + kB * kNH), blk, 0,
                    stream>>>(zx, cw, cb, db, al, xbc, bBm, bCm, dts, acum);
    ssm_y_kernel<<<dim3(1, kN / 64, kB * kNH), blk, 0, stream>>>(
        bCm, bBm, acum, dts, xbc, zx, dd, ybuf);
    // out-proj partials: opart[z] = ybuf @ ow_chunk  (split-K=4, 12 steps,
    // 768 blocks; reduction + gate fused into the NEXT ln_mod — consumer
    // reads each partial exactly once, per the round-11 decision rule)
    mfma_gemm<64, 64><<<dim3(12, 16, 4), blk, 0, stream>>>(
        ybuf, out_wT + (size_t)l * 768 * kDI, nullptr, opart, kD, 384, kDI,
        kD, (size_t)kB * kN * kD);
  }

  // final layer: fold layer-7 out-proj partials (gates from tA7/yA7), then
  // LN with final-layer modulation (tfl, yfl=yA8[:,kOFF_FL:])
  ln_mod_kernel<<<dim3(kB * kN), blk, 0, stream>>>(
      xc, tfl, yA8 + kOFF_FL, xm_bf, 2 * kD, kNCAT, opart,
      (size_t)kB * kN * kD, tA2 + (size_t)7 * kD3, yA8 + (size_t)7 * kD3,
      kNCAT, xc);
  // final projection via MFMA (N=36 pad 128; split-K=4 partial buffers,
  // summed + biased in unpatchify) + scatter
  transposeW_kernel<<<dim3(4, 24, 1), blk, 0, stream>>>(fl_lin_w, Wt, kD, 36,
                                                        0, 0);
  mfma_gemm<64, 128><<<dim3(1, 16, 4), blk, 0, stream>>>(
      xm_bf, Wt, nullptr, fpp, 36, 192, kD, 36, (size_t)kB * kN * 36);
  unpatchify_kernel<<<dim3((kB * kN * 36 + 255) / 256), blk, 0, stream>>>(
      fpp, fl_lin_b, out);

  // hf-nets via implicit-GEMM MFMA
  const float* w1s[3] = {(const float*)d_in[29], (const float*)d_in[35],
                         (const float*)d_in[41]};
  const float* b1s[3] = {(const float*)d_in[30], (const float*)d_in[36],
                         (const float*)d_in[42]};
  const float* w2s[3] = {(const float*)d_in[31], (const float*)d_in[37],
                         (const float*)d_in[43]};
  const float* b2s[3] = {(const float*)d_in[32], (const float*)d_in[38],
                         (const float*)d_in[44]};
  const float* w3s[3] = {(const float*)d_in[33], (const float*)d_in[39],
                         (const float*)d_in[45]};
  const float* b3s[3] = {(const float*)d_in[34], (const float*)d_in[40],
                         (const float*)d_in[46]};
  convw_prep_kernel<<<dim3((3 * 128 * 576 + 255) / 256, 1, 2), blk, 0,
                      stream>>>(w2s[0], w2s[1], w2s[2], w3s[0], w3s[1],
                                w3s[2], Bt2, Bt3);
  conv1_kernel<<<dim3(3 * 4096 * 64 / 256), blk, 0, stream>>>(
      H[0], H[1], H[2], w1s[0], w1s[1], w1s[2], b1s[0], b1s[1], b1s[2], c1bf);
  conv_gemm<0><<<dim3(1, 32, 3), blk, 0, stream>>>(
      c1bf, Bt2, b2s[0], b2s[1], b2s[2], nullptr, nullptr, nullptr, c2bf,
      nullptr);
  conv_gemm<1><<<dim3(1, 32, 3), blk, 0, stream>>>(
      c2bf, Bt3, b3s[0], b3s[1], b3s[2], H[0], H[1], H[2], nullptr, out);
}